// Round 2
// baseline (339.598 us; speedup 1.0000x reference)
//
#include <hip/hip_runtime.h>
#include <stdint.h>

#define B_    4
#define N_    2048
#define D_    4096
#define E_    64
#define TOKENS (B_ * N_)        // 8192
#define KT    32                // K-tile staged in LDS
#define TM    128               // tokens per block tile
#define KS    8                 // split-K factor (DO NOT CHANGE: logit bit-exactness)
#define KCHUNK (D_ / KS)        // 512
#define NITER (KCHUNK / KT)     // 16

typedef float vfloat4 __attribute__((ext_vector_type(4)));  // native vec for NT stores

// global -> LDS direct DMA, 16B per lane, wave-uniform LDS base + lane*16
#define GL2LDS16(g, s) __builtin_amdgcn_global_load_lds(                     \
    (const __attribute__((address_space(1))) void*)(g),                      \
    (__attribute__((address_space(3))) void*)(s), 16, 0, 0)

// ---------------------------------------------------------------------------
// K1: split-K fp32 GEMM fused with d_out zero-fill.
// 256 threads (4 waves), tile 128 tok x 64 experts, thread tile 8 tok x 4 exp.
// Round-2 change: Round 1 proved the LDS-conflict/DMA design (conflicts
// 3.1M -> 0) but dropped to 1 wave/SIMD (Occupancy 9.3%) -> latency-bound at
// VALUBusy 29%. Halving the per-thread tile (64 -> 32 outputs) doubles wave
// count: 2048 waves = 8/CU = 2/SIMD, 2 blocks/CU, restoring TLP while keeping
//   - global_load_lds width=16 staging (zero ds_write instructions),
//   - XOR-swizzled conflict-free A-fragment ds_read_b128,
//   - double-buffered LDS (48 KB), prefetch issued before compute.
// LDS read budget: 1.5 B/FMA -> ~3k LDS cycles/CU/iter vs 4k FMA cycles/SIMD
// -> still FMA-issue-bound, not LDS-bound.
// Accumulation order per (token,expert,kc) unchanged (ascending k, fp32 fmac)
// -> logits bit-identical.
// Each block also streams its 20480-float4 slice of d_out as zeros (NT),
// interleaved with the K-loop. Block 0 zeroes probsum + the two loss slots.
// ---------------------------------------------------------------------------
__global__ __launch_bounds__(256) void k_gemm_z(const float* __restrict__ A,
                                                const float* __restrict__ W,
                                                float* __restrict__ P,
                                                float* __restrict__ out,
                                                float* __restrict__ probsum,
                                                float* __restrict__ losses) {
    __shared__ float As[2][TM][KT];   // [tok][16B-slot swizzled], DMA-linear
    __shared__ float Ws[2][KT][E_];   // global-contiguous tile, DMA-linear

    const int tid   = threadIdx.x;
    const int l     = tid & 63;        // lane
    const int w     = tid >> 6;        // wave 0..3
    const int tok0  = blockIdx.x * TM;
    const int kc    = blockIdx.y;
    const int kbase = kc * KCHUNK;
    const int blin  = kc * gridDim.x + blockIdx.x;   // 0..511

    const int t0 = (tid >> 4) * 8;     // token offset 0..120
    const int e0 = (tid & 15) * 4;     // expert offset 0..60
    const int sw = (tid >> 4) & 7;     // read-side swizzle key = (tok>>3)&7

    // --- DMA source pointers (advance by KT each iter) ---------------------
    // A: issue i (= w*4+q, 0..15) covers tokens i*8..i*8+7; lane l ->
    //    tok i*8+(l>>3), slot l&7; source k4 = (l&7)^(i&7) so that
    //    LDS[tok][slot] holds k4 = slot ^ ((tok>>3)&7).
    const float* pA[4];
    #pragma unroll
    for (int q = 0; q < 4; ++q) {
        const int i  = w * 4 + q;
        const int tk = i * 8 + (l >> 3);
        const int ks = (l & 7) ^ (i & 7);
        pA[q] = A + (size_t)(tok0 + tk) * D_ + kbase + ks * 4;
    }
    // W: tile is 8 KB contiguous in global; issue j (= w*2+q, 0..7) covers
    //    rows j*4..j*4+3 (1 KB each), linear (2-way read aliasing is free).
    const float* pW[2];
    #pragma unroll
    for (int q = 0; q < 2; ++q) {
        const int j  = w * 2 + q;
        const int kk = j * 4 + (l >> 4);
        pW[q] = W + (size_t)(kbase + kk) * E_ + (l & 15) * 4;
    }

    // zero-fill: block covers float4 range [blin*20480, (blin+1)*20480)
    vfloat4* zbase = reinterpret_cast<vfloat4*>(out) + (size_t)blin * 20480 + tid;
    const vfloat4 z4 = {0.f, 0.f, 0.f, 0.f};

    if (blin == 0) {
        probsum[tid] = 0.f;            // 256 entries, 256 threads
        if (tid < 2) losses[tid] = 0.f;
    }

    // prologue: stage tile 0 into buf 0
    #pragma unroll
    for (int q = 0; q < 4; ++q) {
        GL2LDS16(pA[q], &As[0][(w * 4 + q) * 8][0]);
        pA[q] += KT;
    }
    #pragma unroll
    for (int q = 0; q < 2; ++q) {
        GL2LDS16(pW[q], &Ws[0][(w * 2 + q) * 4][0]);
        pW[q] += KT * E_;
    }
    __syncthreads();                   // vmcnt(0) drain -> buf0 ready

    float acc[8][4];
    #pragma unroll
    for (int i = 0; i < 8; ++i)
        #pragma unroll
        for (int j = 0; j < 4; ++j) acc[i][j] = 0.f;

    #pragma unroll 1
    for (int kt = 0; kt < NITER; ++kt) {
        const int cur = kt & 1;
        const int nxt = cur ^ 1;

        // issue next-tile DMA first: whole compute phase hides the latency
        if (kt + 1 < NITER) {
            #pragma unroll
            for (int q = 0; q < 4; ++q) {
                GL2LDS16(pA[q], &As[nxt][(w * 4 + q) * 8][0]);
                pA[q] += KT;
            }
            #pragma unroll
            for (int q = 0; q < 2; ++q) {
                GL2LDS16(pW[q], &Ws[nxt][(w * 2 + q) * 4][0]);
                pW[q] += KT * E_;
            }
        }

        // interleaved zero stores: 5/iter * 16 iters = 80 = 20480/256
        #pragma unroll
        for (int j = 0; j < 5; ++j)
            __builtin_nontemporal_store(z4, zbase + (size_t)(kt * 5 + j) * 256);

        #pragma unroll
        for (int kk4 = 0; kk4 < 8; ++kk4) {
            float4 av[8];
            const int so = ((kk4 ^ sw) << 2);   // swizzled 16B slot
            #pragma unroll
            for (int i = 0; i < 8; ++i)
                av[i] = *reinterpret_cast<const float4*>(&As[cur][t0 + i][so]);
            #pragma unroll
            for (int k = 0; k < 4; ++k) {       // kk = kt*KT + kk4*4 + k, ascending
                const float4 w0 = *reinterpret_cast<const float4*>(&Ws[cur][kk4 * 4 + k][e0]);
                #pragma unroll
                for (int i = 0; i < 8; ++i) {
                    const float a = (k == 0) ? av[i].x : (k == 1) ? av[i].y
                                  : (k == 2) ? av[i].z : av[i].w;
                    acc[i][0] += a * w0.x; acc[i][1] += a * w0.y;
                    acc[i][2] += a * w0.z; acc[i][3] += a * w0.w;
                }
            }
        }
        __syncthreads();               // drains this iter's DMA for next iter
    }

    float* base = P + ((size_t)kc * TOKENS + tok0) * E_;
    #pragma unroll
    for (int i = 0; i < 8; ++i)
        *reinterpret_cast<float4*>(&base[(size_t)(t0 + i) * E_ + e0]) =
            make_float4(acc[i][0], acc[i][1], acc[i][2], acc[i][3]);
}

// ---------------------------------------------------------------------------
// K2: reduce split-K partials; per-token softmax stats (wave per token, lane =
// expert). Writes argmax idx, gate (=max prob), accumulates probsum[b][e] and
// the z-loss (atomic, pre-scaled). UNCHANGED.
// ---------------------------------------------------------------------------
__global__ __launch_bounds__(256) void k_softmax(const float* __restrict__ P,
                                                 int* __restrict__ idx,
                                                 float* __restrict__ gate,
                                                 float* __restrict__ probsum,
                                                 float* __restrict__ out_z) {
    const int tid  = threadIdx.x;
    const int wid  = tid >> 6;
    const int lane = tid & 63;
    const int tok  = blockIdx.x * 4 + wid;

    float l = 0.f;
    #pragma unroll
    for (int kc = 0; kc < KS; ++kc)
        l += P[((size_t)kc * TOKENS + tok) * E_ + lane];

    // wave argmax, first-index tie-break (matches numpy)
    float m = l; int mi = lane;
    #pragma unroll
    for (int off = 32; off > 0; off >>= 1) {
        const float om = __shfl_down(m, off);
        const int   oi = __shfl_down(mi, off);
        if (om > m || (om == m && oi < mi)) { m = om; mi = oi; }
    }
    m  = __shfl(m, 0);
    mi = __shfl(mi, 0);

    const float p = __expf(l - m);
    float s = p;
    #pragma unroll
    for (int off = 32; off > 0; off >>= 1) s += __shfl_down(s, off);
    s = __shfl(s, 0);

    __shared__ float pacc[4][E_];
    __shared__ float zv[4];
    pacc[wid][lane] = p / s;
    if (lane == 0) {
        const float lse = m + logf(s);
        zv[wid]   = lse * lse;
        idx[tok]  = mi;
        gate[tok] = 1.0f / s;                 // exp(m-m)/s = max prob
    }
    __syncthreads();

    if (tid < E_) {
        const float ps = pacc[0][tid] + pacc[1][tid] + pacc[2][tid] + pacc[3][tid];
        const int b = (blockIdx.x * 4) / N_;  // block never crosses batch
        atomicAdd(&probsum[b * E_ + tid], ps);
    }
    if (tid == 0)
        atomicAdd(out_z, (zv[0] + zv[1] + zv[2] + zv[3]) * (1.0f / (float)TOKENS));
}

// ---------------------------------------------------------------------------
// K3: ordered position-in-expert via wave ballot (matches reference cumsum),
// scatter into dispatch/combine + aux-loss fused. One wave per (b,e).
// UNCHANGED.
// ---------------------------------------------------------------------------
__global__ __launch_bounds__(64) void k_posloss(const int* __restrict__ idx,
                                                const float* __restrict__ gate,
                                                const float* __restrict__ probsum,
                                                float* __restrict__ out,
                                                float* __restrict__ out_aux,
                                                int C, size_t half) {
    const int b = blockIdx.x >> 6;
    const int e = blockIdx.x & 63;
    const int lane = threadIdx.x;
    const int*   ib = idx  + b * N_;
    const float* gb = gate + b * N_;
    float* ob = out + (size_t)b * N_ * E_ * C;   // dispatch base for batch b

    int running = 0;
    for (int step = 0; step < N_ / 64; ++step) {
        const int t = step * 64 + lane;
        const bool match = (ib[t] == e);
        const unsigned long long mask = __ballot(match);
        if (match) {
            const int p = running + __popcll(mask & ((1ull << lane) - 1ull));
            if (p < C) {
                const size_t off = (size_t)t * E_ * C + (size_t)e * C + p;
                ob[off] = 1.0f;            // dispatch
                ob[half + off] = gb[t];    // combine
            }
        }
        running += __popcll(mask);
    }
    if (lane == 0)   // aux = sum(count * probsum) * E^2/(B*E*N*N) = sum/262144
        atomicAdd(out_aux,
                  (float)running * probsum[b * E_ + e] * (1.0f / 262144.0f));
}

// ---------------------------------------------------------------------------
extern "C" void kernel_launch(void* const* d_in, const int* in_sizes, int n_in,
                              void* d_out, int out_size, void* d_ws, size_t ws_size,
                              hipStream_t stream) {
    const float* A = (const float*)d_in[0];
    const float* W = (const float*)d_in[1];
    float* out = (float*)d_out;

    const size_t half = ((size_t)out_size - 2) / 2;          // TOKENS*E*C
    const int C = (int)(half / ((size_t)TOKENS * E_));       // 40

    float* P = (float*)d_ws;
    size_t off = (size_t)KS * TOKENS * E_;
    int*   idx     = (int*)(P + off);   off += TOKENS;
    float* gate    = P + off;           off += TOKENS;
    float* probsum = P + off;           off += B_ * E_;

    float* out_aux = out + 2 * half;
    float* out_z   = out + 2 * half + 1;

    // k_gemm_z zeroes all of d_out (2*half floats via per-block NT-store
    // slices; 2*half = 41,943,040 floats = 512 blocks * 20480 float4 exactly)
    // plus probsum and the two loss scalars (block 0). No hipMemsetAsync.
    k_gemm_z<<<dim3(TOKENS / TM, KS), 256, 0, stream>>>(A, W, P, out, probsum,
                                                        out_aux);
    k_softmax<<<TOKENS / 4, 256, 0, stream>>>(P, idx, gate, probsum, out_z);
    k_posloss<<<B_ * E_, 64, 0, stream>>>(idx, gate, probsum, out, out_aux, C, half);
}

// Round 3
// 318.821 us; speedup vs baseline: 1.0652x; 1.0652x over previous
//
#include <hip/hip_runtime.h>
#include <stdint.h>

#define B_    4
#define N_    2048
#define D_    4096
#define E_    64
#define TOKENS (B_ * N_)        // 8192
#define KT    32                // K-tile staged in LDS
#define TM    128               // tokens per block tile
#define KS    8                 // split-K factor (DO NOT CHANGE: logit bit-exactness)
#define KCHUNK (D_ / KS)        // 512
#define NITER (KCHUNK / KT)     // 16

typedef float vfloat4 __attribute__((ext_vector_type(4)));  // native vec for NT stores

// global -> LDS direct DMA, 16B per lane, wave-uniform LDS base + lane*16
#define GL2LDS16(g, s) __builtin_amdgcn_global_load_lds(                     \
    (const __attribute__((address_space(1))) void*)(g),                      \
    (__attribute__((address_space(3))) void*)(s), 16, 0, 0)

// ---------------------------------------------------------------------------
// K1: split-K fp32 GEMM fused with d_out zero-fill. UNCHANGED from Round 2
// (108 us, conflicts 0, the isolated variable this round is K2).
// ---------------------------------------------------------------------------
__global__ __launch_bounds__(256) void k_gemm_z(const float* __restrict__ A,
                                                const float* __restrict__ W,
                                                float* __restrict__ P,
                                                float* __restrict__ out,
                                                float* __restrict__ probsum,
                                                float* __restrict__ losses) {
    __shared__ float As[2][TM][KT];   // [tok][16B-slot swizzled], DMA-linear
    __shared__ float Ws[2][KT][E_];   // global-contiguous tile, DMA-linear

    const int tid   = threadIdx.x;
    const int l     = tid & 63;        // lane
    const int w     = tid >> 6;        // wave 0..3
    const int tok0  = blockIdx.x * TM;
    const int kc    = blockIdx.y;
    const int kbase = kc * KCHUNK;
    const int blin  = kc * gridDim.x + blockIdx.x;   // 0..511

    const int t0 = (tid >> 4) * 8;     // token offset 0..120
    const int e0 = (tid & 15) * 4;     // expert offset 0..60
    const int sw = (tid >> 4) & 7;     // read-side swizzle key = (tok>>3)&7

    // --- DMA source pointers (advance by KT each iter) ---------------------
    // A: issue i (= w*4+q, 0..15) covers tokens i*8..i*8+7; lane l ->
    //    tok i*8+(l>>3), slot l&7; source k4 = (l&7)^(i&7) so that
    //    LDS[tok][slot] holds k4 = slot ^ ((tok>>3)&7).
    const float* pA[4];
    #pragma unroll
    for (int q = 0; q < 4; ++q) {
        const int i  = w * 4 + q;
        const int tk = i * 8 + (l >> 3);
        const int ks = (l & 7) ^ (i & 7);
        pA[q] = A + (size_t)(tok0 + tk) * D_ + kbase + ks * 4;
    }
    // W: tile is 8 KB contiguous in global; issue j (= w*2+q, 0..7) covers
    //    rows j*4..j*4+3 (1 KB each), linear (2-way read aliasing is free).
    const float* pW[2];
    #pragma unroll
    for (int q = 0; q < 2; ++q) {
        const int j  = w * 2 + q;
        const int kk = j * 4 + (l >> 4);
        pW[q] = W + (size_t)(kbase + kk) * E_ + (l & 15) * 4;
    }

    // zero-fill: block covers float4 range [blin*20480, (blin+1)*20480)
    vfloat4* zbase = reinterpret_cast<vfloat4*>(out) + (size_t)blin * 20480 + tid;
    const vfloat4 z4 = {0.f, 0.f, 0.f, 0.f};

    if (blin == 0) {
        probsum[tid] = 0.f;            // 256 entries, 256 threads
        if (tid < 2) losses[tid] = 0.f;
    }

    // prologue: stage tile 0 into buf 0
    #pragma unroll
    for (int q = 0; q < 4; ++q) {
        GL2LDS16(pA[q], &As[0][(w * 4 + q) * 8][0]);
        pA[q] += KT;
    }
    #pragma unroll
    for (int q = 0; q < 2; ++q) {
        GL2LDS16(pW[q], &Ws[0][(w * 2 + q) * 4][0]);
        pW[q] += KT * E_;
    }
    __syncthreads();                   // vmcnt(0) drain -> buf0 ready

    float acc[8][4];
    #pragma unroll
    for (int i = 0; i < 8; ++i)
        #pragma unroll
        for (int j = 0; j < 4; ++j) acc[i][j] = 0.f;

    #pragma unroll 1
    for (int kt = 0; kt < NITER; ++kt) {
        const int cur = kt & 1;
        const int nxt = cur ^ 1;

        // issue next-tile DMA first: whole compute phase hides the latency
        if (kt + 1 < NITER) {
            #pragma unroll
            for (int q = 0; q < 4; ++q) {
                GL2LDS16(pA[q], &As[nxt][(w * 4 + q) * 8][0]);
                pA[q] += KT;
            }
            #pragma unroll
            for (int q = 0; q < 2; ++q) {
                GL2LDS16(pW[q], &Ws[nxt][(w * 2 + q) * 4][0]);
                pW[q] += KT * E_;
            }
        }

        // interleaved zero stores: 5/iter * 16 iters = 80 = 20480/256
        #pragma unroll
        for (int j = 0; j < 5; ++j)
            __builtin_nontemporal_store(z4, zbase + (size_t)(kt * 5 + j) * 256);

        #pragma unroll
        for (int kk4 = 0; kk4 < 8; ++kk4) {
            float4 av[8];
            const int so = ((kk4 ^ sw) << 2);   // swizzled 16B slot
            #pragma unroll
            for (int i = 0; i < 8; ++i)
                av[i] = *reinterpret_cast<const float4*>(&As[cur][t0 + i][so]);
            #pragma unroll
            for (int k = 0; k < 4; ++k) {       // kk = kt*KT + kk4*4 + k, ascending
                const float4 w0 = *reinterpret_cast<const float4*>(&Ws[cur][kk4 * 4 + k][e0]);
                #pragma unroll
                for (int i = 0; i < 8; ++i) {
                    const float a = (k == 0) ? av[i].x : (k == 1) ? av[i].y
                                  : (k == 2) ? av[i].z : av[i].w;
                    acc[i][0] += a * w0.x; acc[i][1] += a * w0.y;
                    acc[i][2] += a * w0.z; acc[i][3] += a * w0.w;
                }
            }
        }
        __syncthreads();               // drains this iter's DMA for next iter
    }

    float* base = P + ((size_t)kc * TOKENS + tok0) * E_;
    #pragma unroll
    for (int i = 0; i < 8; ++i)
        *reinterpret_cast<float4*>(&base[(size_t)(t0 + i) * E_ + e0]) =
            make_float4(acc[i][0], acc[i][1], acc[i][2], acc[i][3]);
}

// ---------------------------------------------------------------------------
// K2: reduce split-K partials; per-token softmax stats. ROUND-3 REDESIGN:
// Round 0-2 launched 2048 blocks, each doing 64 probsum atomicAdds ->
// 131,072 device-scope atomics onto 1 KB of L2 lines (theory: the hidden
// ~100+ us). Now 256 blocks x 32 tokens: each wave owns 8 tokens serially,
// keeps its per-expert prob partial (lane=expert) in a register, LDS-reduce
// across the 4 waves, ONE atomicAdd per (block,expert) -> 16,384 atomics
// (8x fewer); out_z atomics 2048 -> 256.
// Per-token math is instruction-identical (kc-ascending l sum, same argmax
// tie-break, gate=1/s) -> idx/gate bit-exact -> dispatch/combine unchanged.
// probsum/z change only in (already nondeterministic) summation order.
// ---------------------------------------------------------------------------
__global__ __launch_bounds__(256) void k_softmax(const float* __restrict__ P,
                                                 int* __restrict__ idx,
                                                 float* __restrict__ gate,
                                                 float* __restrict__ probsum,
                                                 float* __restrict__ out_z) {
    const int tid  = threadIdx.x;
    const int wid  = tid >> 6;
    const int lane = tid & 63;
    const int tok0 = blockIdx.x * 32 + wid * 8;   // 8 tokens per wave

    float ps = 0.f;   // per-lane (=expert) probsum partial over 8 tokens
    float zz = 0.f;   // per-wave z partial (accumulated on lane 0)

    #pragma unroll
    for (int t = 0; t < 8; ++t) {
        const int tok = tok0 + t;

        float l = 0.f;
        #pragma unroll
        for (int kc = 0; kc < KS; ++kc)
            l += P[((size_t)kc * TOKENS + tok) * E_ + lane];

        // wave argmax, first-index tie-break (matches numpy)
        float m = l; int mi = lane;
        #pragma unroll
        for (int off = 32; off > 0; off >>= 1) {
            const float om = __shfl_down(m, off);
            const int   oi = __shfl_down(mi, off);
            if (om > m || (om == m && oi < mi)) { m = om; mi = oi; }
        }
        m  = __shfl(m, 0);
        mi = __shfl(mi, 0);

        const float p = __expf(l - m);
        float s = p;
        #pragma unroll
        for (int off = 32; off > 0; off >>= 1) s += __shfl_down(s, off);
        s = __shfl(s, 0);

        ps += p / s;
        if (lane == 0) {
            const float lse = m + logf(s);
            zz += lse * lse;
            idx[tok]  = mi;
            gate[tok] = 1.0f / s;             // exp(m-m)/s = max prob
        }
    }

    __shared__ float pacc[4][E_];
    __shared__ float zv[4];
    pacc[wid][lane] = ps;
    if (lane == 0) zv[wid] = zz;
    __syncthreads();

    if (tid < E_) {
        const float v = pacc[0][tid] + pacc[1][tid] + pacc[2][tid] + pacc[3][tid];
        const int b = (blockIdx.x * 32) / N_;  // block never crosses batch
        atomicAdd(&probsum[b * E_ + tid], v);
    }
    if (tid == 0)
        atomicAdd(out_z, (zv[0] + zv[1] + zv[2] + zv[3]) * (1.0f / (float)TOKENS));
}

// ---------------------------------------------------------------------------
// K3: ordered position-in-expert via wave ballot (matches reference cumsum),
// scatter into dispatch/combine + aux-loss fused. One wave per (b,e).
// UNCHANGED.
// ---------------------------------------------------------------------------
__global__ __launch_bounds__(64) void k_posloss(const int* __restrict__ idx,
                                                const float* __restrict__ gate,
                                                const float* __restrict__ probsum,
                                                float* __restrict__ out,
                                                float* __restrict__ out_aux,
                                                int C, size_t half) {
    const int b = blockIdx.x >> 6;
    const int e = blockIdx.x & 63;
    const int lane = threadIdx.x;
    const int*   ib = idx  + b * N_;
    const float* gb = gate + b * N_;
    float* ob = out + (size_t)b * N_ * E_ * C;   // dispatch base for batch b

    int running = 0;
    for (int step = 0; step < N_ / 64; ++step) {
        const int t = step * 64 + lane;
        const bool match = (ib[t] == e);
        const unsigned long long mask = __ballot(match);
        if (match) {
            const int p = running + __popcll(mask & ((1ull << lane) - 1ull));
            if (p < C) {
                const size_t off = (size_t)t * E_ * C + (size_t)e * C + p;
                ob[off] = 1.0f;            // dispatch
                ob[half + off] = gb[t];    // combine
            }
        }
        running += __popcll(mask);
    }
    if (lane == 0)   // aux = sum(count * probsum) * E^2/(B*E*N*N) = sum/262144
        atomicAdd(out_aux,
                  (float)running * probsum[b * E_ + e] * (1.0f / 262144.0f));
}

// ---------------------------------------------------------------------------
extern "C" void kernel_launch(void* const* d_in, const int* in_sizes, int n_in,
                              void* d_out, int out_size, void* d_ws, size_t ws_size,
                              hipStream_t stream) {
    const float* A = (const float*)d_in[0];
    const float* W = (const float*)d_in[1];
    float* out = (float*)d_out;

    const size_t half = ((size_t)out_size - 2) / 2;          // TOKENS*E*C
    const int C = (int)(half / ((size_t)TOKENS * E_));       // 40

    float* P = (float*)d_ws;
    size_t off = (size_t)KS * TOKENS * E_;
    int*   idx     = (int*)(P + off);   off += TOKENS;
    float* gate    = P + off;           off += TOKENS;
    float* probsum = P + off;           off += B_ * E_;

    float* out_aux = out + 2 * half;
    float* out_z   = out + 2 * half + 1;

    // k_gemm_z zeroes all of d_out (2*half floats via per-block NT-store
    // slices; 2*half = 41,943,040 floats = 512 blocks * 20480 float4 exactly)
    // plus probsum and the two loss scalars (block 0). No hipMemsetAsync.
    k_gemm_z<<<dim3(TOKENS / TM, KS), 256, 0, stream>>>(A, W, P, out, probsum,
                                                        out_aux);
    k_softmax<<<TOKENS / 32, 256, 0, stream>>>(P, idx, gate, probsum, out_z);
    k_posloss<<<B_ * E_, 64, 0, stream>>>(idx, gate, probsum, out, out_aux, C, half);
}